// Round 5
// baseline (699.104 us; speedup 1.0000x reference)
//
#include <hip/hip_runtime.h>

// DE3: out[0] = B * (8 + sum_i p_i*log2(p_i)), p_i = hist_i / (H*W),
// hist over floor(img) in [0,256), img is (16,2048,2048) fp32 = 268 MB.
// Memory-bound streaming reduction: floor ~43 us @ 6.3 TB/s.
//
// R5: REVERT nontemporal loads (R4 post-mortem: VGPR=12, loads serialized,
// 292us). Plain vector loads, 4 independent 16B loads in flight per thread,
// branchless bin update (overflow bin 256 instead of predicated atomics).
// Keep fused hist+entropy via last-block ticket.

#define NBINS 256
#define HIST_BLOCKS 2048
#define HIST_THREADS 256

typedef float f32x4 __attribute__((ext_vector_type(4)));

__global__ void zero_hist(unsigned int* __restrict__ hist) {
    // [0..255] bins, [256] completion ticket. d_ws is re-poisoned to 0xAA
    // before every timed launch, so this must run every call.
    hist[threadIdx.x] = 0u;
    if (threadIdx.x == 0) hist[NBINS] = 0u;
}

__device__ __forceinline__ void bump(unsigned int* lh, float v) {
    // truncation == floor for v >= 0; out-of-range -> dummy bin 256.
    int bin = (int)v;
    bool ok = (v >= 0.0f) && (v < 256.0f);
    bin = ok ? bin : NBINS;          // v_cmp + v_cndmask, no exec-mask dance
    atomicAdd(&lh[bin], 1u);
}

__global__ __launch_bounds__(HIST_THREADS) void hist_entropy_kernel(
        const float* __restrict__ img,
        unsigned int* __restrict__ ghist,
        float* __restrict__ out,
        int n_vec4, long long n_total,
        float B, float inv_temp) {
    // One private LDS histogram per wave (4 waves/block), 257 entries each
    // (bin 256 = out-of-range sink, never merged). ~4.1 KiB LDS/block.
    __shared__ unsigned int lhist[4][NBINS + 1];
    const int t = threadIdx.x;
    unsigned int* lh = lhist[t >> 6];

    for (int i = t; i < 4 * (NBINS + 1); i += HIST_THREADS)
        ((unsigned int*)lhist)[i] = 0u;
    __syncthreads();

    const f32x4* __restrict__ img4 = (const f32x4*)img;
    const int tid = blockIdx.x * HIST_THREADS + t;
    const int stride = gridDim.x * HIST_THREADS;

    // 4x-unrolled grid-stride: four independent 16B loads issued before the
    // LDS-atomic burst -> 64 B/thread in flight, staged vmcnt waits.
    int i = tid;
    for (; i + 3 * stride < n_vec4; i += 4 * stride) {
        f32x4 a = img4[i];
        f32x4 b = img4[i + stride];
        f32x4 c = img4[i + 2 * stride];
        f32x4 d = img4[i + 3 * stride];
        #pragma unroll
        for (int k = 0; k < 4; ++k) bump(lh, a[k]);
        #pragma unroll
        for (int k = 0; k < 4; ++k) bump(lh, b[k]);
        #pragma unroll
        for (int k = 0; k < 4; ++k) bump(lh, c[k]);
        #pragma unroll
        for (int k = 0; k < 4; ++k) bump(lh, d[k]);
    }
    for (; i < n_vec4; i += stride) {
        f32x4 a = img4[i];
        #pragma unroll
        for (int k = 0; k < 4; ++k) bump(lh, a[k]);
    }
    // Scalar tail (n_total % 4): no-op at this problem size.
    for (long long j = 4LL * n_vec4 + tid; j < n_total; j += stride)
        bump(lh, img[j]);

    __syncthreads();
    unsigned int s = lhist[0][t] + lhist[1][t] + lhist[2][t] + lhist[3][t];
    if (s) atomicAdd(&ghist[t], s);

    // Last-block ticket: device-scope fence so our ghist adds are visible,
    // then the last block computes the entropy inline.
    __threadfence();
    __shared__ unsigned int ticket;
    if (t == 0) ticket = atomicAdd(&ghist[NBINS], 1u);
    __syncthreads();
    if (ticket == (unsigned int)(gridDim.x - 1)) {
        // Atomic read (add 0) bypasses stale caches across XCDs.
        unsigned int c = atomicAdd(&ghist[t], 0u);
        float term = 0.0f;
        if (c > 0u) {
            float p = (float)c * inv_temp;
            term = p * __log2f(p);
        }
        #pragma unroll
        for (int off = 32; off > 0; off >>= 1)
            term += __shfl_down(term, off, 64);
        __shared__ float wsum[4];
        if ((t & 63) == 0) wsum[t >> 6] = term;
        __syncthreads();
        if (t == 0) {
            float ssum = wsum[0] + wsum[1] + wsum[2] + wsum[3];
            out[0] = B * (8.0f + ssum);  // res = -ssum
        }
    }
}

extern "C" void kernel_launch(void* const* d_in, const int* in_sizes, int n_in,
                              void* d_out, int out_size, void* d_ws, size_t ws_size,
                              hipStream_t stream) {
    const float* img = (const float*)d_in[0];
    float* out = (float*)d_out;
    unsigned int* ghist = (unsigned int*)d_ws;  // 257 u32 of scratch

    const long long n = (long long)in_sizes[0];   // B*H*W = 67,108,864
    const long long HW = 2048LL * 2048LL;         // temp = H*W (fixed shape)
    const float B = (float)(n / HW);              // 16
    const float inv_temp = 1.0f / (float)HW;
    const int n_vec4 = (int)(n / 4);

    zero_hist<<<dim3(1), dim3(NBINS), 0, stream>>>(ghist);
    hist_entropy_kernel<<<dim3(HIST_BLOCKS), dim3(HIST_THREADS), 0, stream>>>(
        img, ghist, out, n_vec4, n, B, inv_temp);
}

// Round 6
// 368.369 us; speedup vs baseline: 1.8978x; 1.8978x over previous
//
#include <hip/hip_runtime.h>

// DE3: out[0] = B * (8 + sum_i p_i*log2(p_i)), p_i = hist_i / (H*W),
// hist over floor(img) in [0,256), img is (16,2048,2048) fp32 = 268 MB.
//
// R6: full revert to the R1 structure (3 kernels, simple loop, DIRECT
// shared-array indexing so atomics stay addrspace(3), no nontemporal, no
// manual unroll — R4/R5 post-mortems showed each of those regressed 2-4x).
// One delta vs R1: 8 sub-histograms (per 32-lane half-wave) to cut LDS
// bank multiplicity on the wave-atomic.

#define NBINS 256
#define HIST_BLOCKS 2048
#define HIST_THREADS 256
#define NSUB 8

__global__ void zero_hist(unsigned int* __restrict__ hist) {
    // d_ws re-poisoned to 0xAA before every timed launch -> zero every call.
    hist[threadIdx.x] = 0u;
}

__global__ __launch_bounds__(HIST_THREADS) void hist_kernel(
        const float* __restrict__ img,
        unsigned int* __restrict__ ghist,
        int n_vec4, long long n_total) {
    // 8 sub-histograms, one per 32-lane half-wave. 257-word rows stagger
    // the bank mapping of row h by h. 8.2 KiB LDS/block.
    __shared__ unsigned int lhist[NSUB][NBINS + 1];
    const int t = threadIdx.x;
    const int sub = t >> 5;

    for (int i = t; i < NSUB * (NBINS + 1); i += HIST_THREADS)
        ((unsigned int*)lhist)[i] = 0u;
    __syncthreads();

    const float4* __restrict__ img4 = (const float4*)img;
    const int tid = blockIdx.x * HIST_THREADS + t;
    const int stride = gridDim.x * HIST_THREADS;

    // Simple grid-stride loop — compiler schedules this well (R1 evidence);
    // every manual-unroll variant regressed. Direct lhist[sub][...] keeps
    // the atomic in LDS address space.
    for (int i = tid; i < n_vec4; i += stride) {
        float4 v = img4[i];
        if (v.x >= 0.0f && v.x < 256.0f) atomicAdd(&lhist[sub][(int)v.x], 1u);
        if (v.y >= 0.0f && v.y < 256.0f) atomicAdd(&lhist[sub][(int)v.y], 1u);
        if (v.z >= 0.0f && v.z < 256.0f) atomicAdd(&lhist[sub][(int)v.z], 1u);
        if (v.w >= 0.0f && v.w < 256.0f) atomicAdd(&lhist[sub][(int)v.w], 1u);
    }
    // Scalar tail (n_total % 4): no-op at this problem size.
    for (long long j = 4LL * n_vec4 + tid; j < n_total; j += stride) {
        float v = img[j];
        if (v >= 0.0f && v < 256.0f) atomicAdd(&lhist[sub][(int)v], 1u);
    }

    __syncthreads();
    unsigned int s = 0;
    #pragma unroll
    for (int h = 0; h < NSUB; ++h) s += lhist[h][t];
    if (s) atomicAdd(&ghist[t], s);
}

__global__ void entropy_kernel(const unsigned int* __restrict__ ghist,
                               float* __restrict__ out,
                               float B, float inv_temp) {
    const int t = threadIdx.x;  // 256 threads, one bin each
    unsigned int c = ghist[t];
    float term = 0.0f;
    if (c > 0u) {
        float p = (float)c * inv_temp;
        term = p * __log2f(p);
    }
    #pragma unroll
    for (int off = 32; off > 0; off >>= 1)
        term += __shfl_down(term, off, 64);
    __shared__ float wsum[4];
    if ((t & 63) == 0) wsum[t >> 6] = term;
    __syncthreads();
    if (t == 0) {
        float s = wsum[0] + wsum[1] + wsum[2] + wsum[3];
        out[0] = B * (8.0f + s);  // res = -s
    }
}

extern "C" void kernel_launch(void* const* d_in, const int* in_sizes, int n_in,
                              void* d_out, int out_size, void* d_ws, size_t ws_size,
                              hipStream_t stream) {
    const float* img = (const float*)d_in[0];
    float* out = (float*)d_out;
    unsigned int* ghist = (unsigned int*)d_ws;  // 256 u32 of scratch

    const long long n = (long long)in_sizes[0];   // B*H*W = 67,108,864
    const long long HW = 2048LL * 2048LL;         // temp = H*W (fixed shape)
    const float B = (float)(n / HW);              // 16
    const float inv_temp = 1.0f / (float)HW;
    const int n_vec4 = (int)(n / 4);

    zero_hist<<<dim3(1), dim3(NBINS), 0, stream>>>(ghist);
    hist_kernel<<<dim3(HIST_BLOCKS), dim3(HIST_THREADS), 0, stream>>>(
        img, ghist, n_vec4, n);
    entropy_kernel<<<dim3(1), dim3(NBINS), 0, stream>>>(ghist, out, B, inv_temp);
}